// Round 1
// baseline (527.768 us; speedup 1.0000x reference)
//
#include <hip/hip_runtime.h>
#include <cstdint>
#include <cstddef>

// ---------------------------------------------------------------------------
// MultiHeadAttention (linear attention + relative position bias, no softmax)
// B=4 S=1024 E=1024 H=16 D=64.  bf16 MFMA pipeline, fp8 Pq intermediate:
//   1. kprep     : x->bf16 ; W_qkv,W_out -> bf16 transposed  (merged)
//   2. kgemm_qkv : qkv = x@Wqkv + b ; scatter q/k (bh,s,d), v DIRECT as vt
//                  8-phase counted-vmcnt pipeline: BM=BN=256, BK=32, 4 LDS
//                  K-tile slots (128 KB), raw s_barrier, vmcnt(8) gates,
//                  setprio around MFMA clusters. grid (12,16), block 512.
//                  Slot rotation: tile g+3 staged into slot freed by tile g-1
//                  after its last barrier -> provably race-free. 64-B LDS rows
//                  are naturally bank-balanced (no swizzle needed).
//   3. kpq       : Pq[bh][x][y] = sum_c pe[x,y,c]*q[bh,x,c] -> fp8, stored
//                  DIRECT from MFMA ACC fragments in permuted-y order
//   4. kattn     : O = ((QK^T + Pq)*scale) @ V ; Pq read as ONE uint4/lane
//   5. kgemm_out : out = attn@Wout + b (fp32)
// NOTE: ~380 us of dur_us is harness per-iteration overhead (1 GiB ws poison
// fill @ ~160 us + input restore); kernel-side total ~140 us vs ~95 us floor.
// ---------------------------------------------------------------------------

typedef unsigned short u16;
typedef unsigned char  u8;
typedef __bf16 bf16x8 __attribute__((ext_vector_type(8)));
typedef float  f32x4  __attribute__((ext_vector_type(4)));
typedef unsigned short u16x8 __attribute__((ext_vector_type(8)));

#define MFMA16(a, b, c) __builtin_amdgcn_mfma_f32_16x16x32_bf16((a), (b), (c), 0, 0, 0)

// async global->LDS, 16 B per lane; LDS dest = wave-uniform base + lane*16
#define GLOAD16(g, l)                                                        \
    __builtin_amdgcn_global_load_lds(                                        \
        (const __attribute__((address_space(1))) unsigned int*)(g),          \
        (__attribute__((address_space(3))) unsigned int*)(l), 16, 0, 0)

__device__ __forceinline__ u16 f2bf(float f) {
    __bf16 h = (__bf16)f;
    return __builtin_bit_cast(u16, h);
}
__device__ __forceinline__ u16x8 pack8(float4 a, float4 b) {
    u16x8 v;
    v[0] = f2bf(a.x); v[1] = f2bf(a.y); v[2] = f2bf(a.z); v[3] = f2bf(a.w);
    v[4] = f2bf(b.x); v[5] = f2bf(b.y); v[6] = f2bf(b.z); v[7] = f2bf(b.w);
    return v;
}

// raw barrier (NO implicit vmcnt(0) drain, unlike __syncthreads)
__device__ __forceinline__ void sbar() {
    asm volatile("" ::: "memory");
    __builtin_amdgcn_s_barrier();
    asm volatile("" ::: "memory");
}
template <int N> __device__ __forceinline__ void waitv() {
    if constexpr (N >= 0)
        asm volatile("s_waitcnt vmcnt(%0)" :: "n"(N) : "memory");
}

// --------------------------------------------------------------------------
// Merged prep: blocks [0,2048): x fp32->bf16 (8 elem/thread)
//              blocks [2048,2816): Wqkv (1024x3072) -> wqkvT (3072x1024) bf16
//              blocks [2816,3072): Wout (1024x1024) -> woutT bf16
// --------------------------------------------------------------------------
__device__ __forceinline__ void convT_tile(const float* __restrict__ in,
                                           u16* __restrict__ out, int R, int C,
                                           int bx, int by, float (*tile)[68]) {
    const int t  = threadIdx.x;
    const int r0 = by * 64, c0 = bx * 64;
    const int rr = t >> 4, c4 = t & 15;
    for (int p = 0; p < 4; ++p) {
        int r = rr + p * 16;
        float4 v = *(const float4*)&in[(size_t)(r0 + r) * C + c0 + c4 * 4];
        *(float4*)&tile[r][c4 * 4] = v;
    }
    __syncthreads();
    for (int p = 0; p < 4; ++p) {
        int n = rr + p * 16;
        ushort4 o;
        o.x = f2bf(tile[c4 * 4 + 0][n]);
        o.y = f2bf(tile[c4 * 4 + 1][n]);
        o.z = f2bf(tile[c4 * 4 + 2][n]);
        o.w = f2bf(tile[c4 * 4 + 3][n]);
        *(ushort4*)&out[(size_t)(c0 + n) * R + r0 + c4 * 4] = o;
    }
}

__global__ __launch_bounds__(256) void kprep(const float* __restrict__ x,
                                             u16* __restrict__ xb,
                                             const float* __restrict__ Wqkv,
                                             u16* __restrict__ wqkvT,
                                             const float* __restrict__ Wout,
                                             u16* __restrict__ woutT) {
    __shared__ float tile[64][68];
    const int bid = blockIdx.x;
    if (bid < 2048) {
        int i = (bid * 256 + threadIdx.x) * 8;
        float4 f0 = *(const float4*)&x[i];
        float4 f1 = *(const float4*)&x[i + 4];
        *(u16x8*)&xb[i] = pack8(f0, f1);
    } else if (bid < 2816) {
        int r = bid - 2048;                       // 48 x 16
        convT_tile(Wqkv, wqkvT, 1024, 3072, r % 48, r / 48, tile);
    } else {
        int r = bid - 2816;                       // 16 x 16
        convT_tile(Wout, woutT, 1024, 1024, r % 16, r / 16, tile);
    }
}

// --------------------------------------------------------------------------
// QKV GEMM, 8-phase pipeline: C(4096x3072) = Xb(bf16) @ WT(3072x1024)^T + b
// BM=BN=256, BK=32. 8 waves (2M x 4N), per-wave C = 128x64 (acc[8][4]).
// LDS: 4 K-tile slots per operand, slot kt&3, 16 KB each -> 128 KB total.
// Per K-tile g: 2 phases x {ds_read subtile, stage half of tile g+3,
//   s_barrier, setprio(1), 16 MFMA, setprio(0), s_barrier}; vmcnt(8) gate
//   once per tile (guards tile g+1, staged 3 tiles = 6 stage-events ago).
// Epilogue: q,k -> (bh,s,d) scatter; v -> vt (bh,d,s) DIRECT (ushort4).
// grid (12,16), block 512
// --------------------------------------------------------------------------
#define STAGE_A(kt) {                                                         \
    u16* d_ = &a_s[(kt) & 3][t * 8];                                          \
    const u16* g_ = &A[(size_t)(m0g + (t >> 2)) * 1024 + (kt) * 32 + (t & 3) * 8]; \
    GLOAD16(g_, d_);                                                          \
    GLOAD16(g_ + (size_t)128 * 1024, d_ + 4096); }

#define STAGE_B(kt) {                                                         \
    u16* d_ = &b_s[(kt) & 3][t * 8];                                          \
    const u16* g_ = &WT[(size_t)(n0g + (t >> 2)) * 1024 + (kt) * 32 + (t & 3) * 8]; \
    GLOAD16(g_, d_);                                                          \
    GLOAD16(g_ + (size_t)128 * 1024, d_ + 4096); }

#define QKV_GROUP(g, DOSTAGE, GATEN)                                          \
  {                                                                           \
    const int s_ = (g) & 3;                                                   \
    /* phase 0: quadrant mf 0-3 x nf 0-3 */                                   \
    _Pragma("unroll")                                                         \
    for (int mf = 0; mf < 4; ++mf)                                            \
      af[mf] = *(const bf16x8*)&a_s[s_][(wr * 128 + mf * 16 + lm) * 32 + lq * 8]; \
    _Pragma("unroll")                                                         \
    for (int nf = 0; nf < 4; ++nf)                                            \
      bfr[nf] = *(const bf16x8*)&b_s[s_][(wc * 64 + nf * 16 + lm) * 32 + lq * 8]; \
    if (DOSTAGE) STAGE_A((g) + 3);                                            \
    sbar();                                                                   \
    __builtin_amdgcn_s_setprio(1);                                            \
    _Pragma("unroll")                                                         \
    for (int mf = 0; mf < 4; ++mf)                                            \
      _Pragma("unroll")                                                       \
      for (int nf = 0; nf < 4; ++nf)                                          \
        acc[mf][nf] = MFMA16(af[mf], bfr[nf], acc[mf][nf]);                   \
    __builtin_amdgcn_s_setprio(0);                                            \
    sbar();                                                                   \
    /* phase 1: quadrant mf 4-7 x nf 0-3 (bfr reused in regs) */              \
    _Pragma("unroll")                                                         \
    for (int mf = 0; mf < 4; ++mf)                                            \
      af[mf] = *(const bf16x8*)&a_s[s_][(wr * 128 + 64 + mf * 16 + lm) * 32 + lq * 8]; \
    if (DOSTAGE) STAGE_B((g) + 3);                                            \
    waitv<GATEN>();                                                           \
    sbar();                                                                   \
    __builtin_amdgcn_s_setprio(1);                                            \
    _Pragma("unroll")                                                         \
    for (int mf = 0; mf < 4; ++mf)                                            \
      _Pragma("unroll")                                                       \
      for (int nf = 0; nf < 4; ++nf)                                          \
        acc[4 + mf][nf] = MFMA16(af[mf], bfr[nf], acc[4 + mf][nf]);           \
    __builtin_amdgcn_s_setprio(0);                                            \
    sbar();                                                                   \
  }

__global__ __launch_bounds__(512, 2) void kgemm_qkv(const u16* __restrict__ A,
                                                    const u16* __restrict__ WT,
                                                    const float* __restrict__ bias,
                                                    u16* __restrict__ qb,
                                                    u16* __restrict__ kb,
                                                    u16* __restrict__ vtb) {
    __shared__ u16 a_s[4][256 * 32];   // 4 K-tile slots x 16 KB = 64 KB
    __shared__ u16 b_s[4][256 * 32];   // 64 KB
    const int t = threadIdx.x;
    const int m0g = blockIdx.y * 256, n0g = blockIdx.x * 256;
    const int lane = t & 63, w = t >> 6, lm = lane & 15, lq = lane >> 4;
    const int wr = w >> 2, wc = w & 3;             // 2 x 4 wave grid

    f32x4 acc[8][4] = {};
    bf16x8 af[4], bfr[4];

    // prologue: stage tiles 0,1,2 (12 loads); wait tile 0 (newest 8 remain)
    STAGE_A(0); STAGE_B(0);
    STAGE_A(1); STAGE_B(1);
    STAGE_A(2); STAGE_B(2);
    waitv<8>();
    sbar();

#pragma unroll 1
    for (int g = 0; g < 29; ++g)
        QKV_GROUP(g, true, 8);
    QKV_GROUP(29, false, 4);   // tile 30 staged @g27; only g28 stages after
    QKV_GROUP(30, false, 0);   // tile 31 staged @g28; nothing after
    QKV_GROUP(31, false, -1);  // last tile, no gate needed

    // epilogue: q,k scatter / v direct transpose
    for (int nf = 0; nf < 4; ++nf) {
        int col = n0g + wc * 64 + nf * 16 + lm;
        float bv = bias[col];
        int which = col >> 10;
        int h = (col >> 6) & 15, d = col & 63;
        for (int mf = 0; mf < 8; ++mf) {
            int row0 = m0g + wr * 128 + mf * 16 + lq * 4;
            int b = row0 >> 10, s = row0 & 1023;
            if (which == 2) {                     // vt[bh][d][s] coalesced ushort4
                ushort4 o;
                o.x = f2bf(acc[mf][nf][0] + bv);
                o.y = f2bf(acc[mf][nf][1] + bv);
                o.z = f2bf(acc[mf][nf][2] + bv);
                o.w = f2bf(acc[mf][nf][3] + bv);
                *(ushort4*)&vtb[((size_t)(b * 16 + h) * 64 + d) * 1024 + s] = o;
            } else {
                u16* dst = (which == 0) ? qb : kb;
                for (int i = 0; i < 4; ++i)
                    dst[((size_t)((b * 16 + h) * 1024 + s + i)) * 64 + d] =
                        f2bf(acc[mf][nf][i] + bv);
            }
        }
    }
}

// --------------------------------------------------------------------------
// Pq[bh][x][y] = sum_c pe[x,y,c]*q[bh,x,c] -> fp8 e4m3 (scale in kattn)
// One block per x; pe streamed once device-wide; double-buffered pe_s,
// ONE barrier/iter; output stored DIRECT from ACC fragments:
//   byte offset within 64-y group = lq*16 + w*4 + i  (y = w*16 + lq*4 + i)
// grid 1024, block 256
// --------------------------------------------------------------------------
__global__ __launch_bounds__(256, 4) void kpq(const u16* __restrict__ qb,
                                              const float* __restrict__ pe,
                                              u8* __restrict__ Pq) {
    __shared__ u16 q_s[64 * 64];
    __shared__ u16 pe_s[2][64 * 80];
    const int x = blockIdx.x;
    const int t = threadIdx.x;
    const int lane = t & 63, w = t >> 6, lm = lane & 15, lq = lane >> 4;
#pragma unroll
    for (int p = 0; p < 2; ++p)
        GLOAD16(&qb[(size_t)((p * 32 + (t >> 3)) * 1024 + x) * 64 + (t & 7) * 8],
                &q_s[p * 2048 + t * 8]);
    const int yl = t >> 2, cq = (t & 3) * 16;
    const float* pex = pe + (size_t)x * 65536;
    float4 r0, r1, r2, r3;
    {
        const float* src = &pex[(size_t)yl * 64 + cq];
        r0 = *(const float4*)&src[0];  r1 = *(const float4*)&src[4];
        r2 = *(const float4*)&src[8];  r3 = *(const float4*)&src[12];
    }
    // per-lane fragment store base: bh = nt*16+lm, row x, group byte lq*16+w*4
    u8* pq_base = Pq + ((size_t)lm * 1024 + x) * 1024 + lq * 16 + w * 4;
    int cur = 0;
    for (int it = 0; it < 16; ++it) {
        *(u16x8*)&pe_s[cur][yl * 80 + cq]     = pack8(r0, r1);
        *(u16x8*)&pe_s[cur][yl * 80 + cq + 8] = pack8(r2, r3);
        __syncthreads();                        // pe_s[cur] ready (covers q_s on it=0)
        if (it < 15) {                          // prefetch next chunk
            const float* src = &pex[(size_t)((it + 1) * 64 + yl) * 64 + cq];
            r0 = *(const float4*)&src[0];  r1 = *(const float4*)&src[4];
            r2 = *(const float4*)&src[8];  r3 = *(const float4*)&src[12];
        }
        // D[y][bh]: wave w owns y-strip [16w, 16w+16)
        f32x4 acc[4] = {};
#pragma unroll
        for (int ks = 0; ks < 2; ++ks) {
            bf16x8 a = *(const bf16x8*)&pe_s[cur][(16 * w + lm) * 80 + ks * 32 + lq * 8];
#pragma unroll
            for (int nt = 0; nt < 4; ++nt) {
                bf16x8 b = *(const bf16x8*)&q_s[(nt * 16 + lm) * 64 + ks * 32 + lq * 8];
                acc[nt] = MFMA16(a, b, acc[nt]);
            }
        }
        // store fragments direct: lane holds bh=nt*16+lm, 4 consecutive y
#pragma unroll
        for (int nt = 0; nt < 4; ++nt) {
            unsigned int pw;
            pw = __builtin_amdgcn_cvt_pk_fp8_f32(acc[nt][0], acc[nt][1], 0u, false);
            pw = __builtin_amdgcn_cvt_pk_fp8_f32(acc[nt][2], acc[nt][3], pw, true);
            *(unsigned int*)&pq_base[(size_t)nt * 16 * 1024 * 1024 + it * 64] = pw;
        }
        cur ^= 1;
    }
}

// --------------------------------------------------------------------------
// Fused attention: O[x,d] = sum_y (q_x.k_y + Pq[x,y])*scale * v[y,d]
// bid = xt*64 + bh  ->  bid%8 = bh%8: all 8 x-tiles of a bh on one XCD.
// Pq: ONE uint4 per (nt,y0) per lane; component mt = y {y0+mt*16+lq*4..+3}.
// grid 512, block 256
// --------------------------------------------------------------------------
__global__ __launch_bounds__(256, 2) void kattn(const u16* __restrict__ qb,
                                                const u16* __restrict__ kb,
                                                const u16* __restrict__ vt,
                                                const u8* __restrict__ Pq,
                                                u16* __restrict__ attnb) {
    __shared__ u16 q_s[128 * 64];
    __shared__ u16 k_s[64 * 64];
    __shared__ u16 v_s[64 * 64];        // vt tile: rows d, cols y
    __shared__ u16 s_s[128 * 80];       // S tile (x rows, y cols), wave-private strips
    const int bid = blockIdx.x;
    const int bh = bid & 63, x0 = (bid >> 6) * 128;
    const int t = threadIdx.x;
    const int lane = t & 63, w = t >> 6, lm = lane & 15, lq = lane >> 4;
    const int sr = t >> 3, sc = (t & 7) * 8;

#pragma unroll
    for (int p = 0; p < 4; ++p)
        GLOAD16(&qb[(size_t)(bh * 1024 + x0 + p * 32 + sr) * 64 + sc],
                &q_s[p * 2048 + t * 8]);

    const u8* PqRow = Pq + ((size_t)(bh * 1024) + x0 + 32 * w + lm) * 1024 + lq * 16;
    f32x4 oacc[2][4] = {};
    for (int y0 = 0; y0 < 1024; y0 += 64) {
        // prefetch Pq fragments: one uint4 per nt (x-row = x0+32w+nt*16+lm)
        uint4 pq4[2];
#pragma unroll
        for (int nt = 0; nt < 2; ++nt)
            pq4[nt] = *(const uint4*)&PqRow[(size_t)(nt * 16) * 1024 + y0];
        __syncthreads();                       // k_s/v_s safe to overwrite
#pragma unroll
        for (int p = 0; p < 2; ++p) {
            GLOAD16(&kb[(size_t)(bh * 1024 + y0 + p * 32 + sr) * 64 + sc],
                    &k_s[p * 2048 + t * 8]);
            GLOAD16(&vt[(size_t)(bh * 64 + p * 32 + sr) * 1024 + y0 + sc],
                    &v_s[p * 2048 + t * 8]);
        }
        __syncthreads();                       // tiles ready (q_s too, first iter)
        // S^T = K.Q^T : D[y][x]; wave w owns x-strip [32w, 32w+32)
        f32x4 sacc[4][2] = {};
#pragma unroll
        for (int ks = 0; ks < 2; ++ks) {
            bf16x8 bq[2];
#pragma unroll
            for (int nt = 0; nt < 2; ++nt)
                bq[nt] = *(const bf16x8*)&q_s[(32 * w + nt * 16 + lm) * 64 + ks * 32 + lq * 8];
#pragma unroll
            for (int mt = 0; mt < 4; ++mt) {
                bf16x8 ak = *(const bf16x8*)&k_s[(mt * 16 + lm) * 64 + ks * 32 + lq * 8];
#pragma unroll
                for (int nt = 0; nt < 2; ++nt)
                    sacc[mt][nt] = MFMA16(ak, bq[nt], sacc[mt][nt]);
            }
        }
        // s = (qk + pq) * scale -> bf16 -> s_s (wave-private strip)
#pragma unroll
        for (int nt = 0; nt < 2; ++nt) {
            int xl = 32 * w + nt * 16 + lm;
            const unsigned int* pqc = (const unsigned int*)&pq4[nt];
#pragma unroll
            for (int mt = 0; mt < 4; ++mt) {
                unsigned int pw = pqc[mt];
                ushort4 o;
                o.x = f2bf((sacc[mt][nt][0] + __builtin_amdgcn_cvt_f32_fp8(pw, 0)) * 0.125f);
                o.y = f2bf((sacc[mt][nt][1] + __builtin_amdgcn_cvt_f32_fp8(pw, 1)) * 0.125f);
                o.z = f2bf((sacc[mt][nt][2] + __builtin_amdgcn_cvt_f32_fp8(pw, 2)) * 0.125f);
                o.w = f2bf((sacc[mt][nt][3] + __builtin_amdgcn_cvt_f32_fp8(pw, 3)) * 0.125f);
                *(ushort4*)&s_s[xl * 80 + mt * 16 + lq * 4] = o;
            }
        }
        // O += S.V  (A = s_s own strip, B = v_s)
#pragma unroll
        for (int ks = 0; ks < 2; ++ks) {
            bf16x8 as[2];
#pragma unroll
            for (int mt = 0; mt < 2; ++mt)
                as[mt] = *(const bf16x8*)&s_s[(32 * w + mt * 16 + lm) * 80 + ks * 32 + lq * 8];
#pragma unroll
            for (int nt = 0; nt < 4; ++nt) {
                bf16x8 bv = *(const bf16x8*)&v_s[(nt * 16 + lm) * 64 + ks * 32 + lq * 8];
#pragma unroll
                for (int mt = 0; mt < 2; ++mt)
                    oacc[mt][nt] = MFMA16(as[mt], bv, oacc[mt][nt]);
            }
        }
    }
    // write attn (B, S, E=h*64+d) bf16
    const int b = bh >> 4, h = bh & 15;
    for (int mt = 0; mt < 2; ++mt) {
        for (int nt = 0; nt < 4; ++nt) {
            int d = nt * 16 + lm;
            for (int i = 0; i < 4; ++i) {
                int s = x0 + 32 * w + mt * 16 + lq * 4 + i;
                attnb[((size_t)(b * 1024 + s)) * 1024 + h * 64 + d] = f2bf(oacc[mt][nt][i]);
            }
        }
    }
}

// --------------------------------------------------------------------------
// Out projection (m97-style): out(4096x1024 fp32) = attn(bf16)@WoutT^T + b
// grid (8,32), block 256
// --------------------------------------------------------------------------
__global__ __launch_bounds__(256, 2) void kgemm_out(const u16* __restrict__ A,
                                                    const u16* __restrict__ WT,
                                                    const float* __restrict__ bias,
                                                    float* __restrict__ out) {
    __shared__ u16 a_s[128 * 64];
    __shared__ u16 b_s[128 * 64];
    const int t = threadIdx.x;
    const int m0 = blockIdx.y * 128, n0 = blockIdx.x * 128;
    const int lane = t & 63, w = t >> 6, lm = lane & 15, lq = lane >> 4;
    const int mb = (w >> 1) * 64, nb = (w & 1) * 64;
    const int sr = t >> 3, sc = (t & 7) * 8;

    f32x4 acc[4][4] = {};
    for (int k0 = 0; k0 < 1024; k0 += 64) {
        __syncthreads();
#pragma unroll
        for (int p = 0; p < 4; ++p) {
            GLOAD16(&A [(size_t)(m0 + p * 32 + sr) * 1024 + k0 + sc], &a_s[p * 2048 + t * 8]);
            GLOAD16(&WT[(size_t)(n0 + p * 32 + sr) * 1024 + k0 + sc], &b_s[p * 2048 + t * 8]);
        }
        __syncthreads();
#pragma unroll
        for (int ks = 0; ks < 2; ++ks) {
            bf16x8 af[4], bfr[4];
#pragma unroll
            for (int mt = 0; mt < 4; ++mt)
                af[mt] = *(const bf16x8*)&a_s[(mb + mt * 16 + lm) * 64 + ks * 32 + lq * 8];
#pragma unroll
            for (int nt = 0; nt < 4; ++nt)
                bfr[nt] = *(const bf16x8*)&b_s[(nb + nt * 16 + lm) * 64 + ks * 32 + lq * 8];
#pragma unroll
            for (int mt = 0; mt < 4; ++mt)
#pragma unroll
                for (int nt = 0; nt < 4; ++nt)
                    acc[mt][nt] = MFMA16(af[mt], bfr[nt], acc[mt][nt]);
        }
    }
    for (int nt = 0; nt < 4; ++nt) {
        int col = n0 + nb + nt * 16 + lm;
        float bv = bias[col];
        for (int mt = 0; mt < 4; ++mt) {
            for (int i = 0; i < 4; ++i) {
                int row = m0 + mb + mt * 16 + lq * 4 + i;
                out[(size_t)row * 1024 + col] = acc[mt][nt][i] + bv;
            }
        }
    }
}

// --------------------------------------------------------------------------
extern "C" void kernel_launch(void* const* d_in, const int* in_sizes, int n_in,
                              void* d_out, int out_size, void* d_ws, size_t ws_size,
                              hipStream_t stream) {
    (void)in_sizes; (void)n_in; (void)out_size; (void)ws_size;
    const float* x    = (const float*)d_in[0];
    const float* Wqkv = (const float*)d_in[1];
    const float* bqkv = (const float*)d_in[2];
    const float* pe   = (const float*)d_in[3];
    const float* Wout = (const float*)d_in[4];
    const float* bout = (const float*)d_in[5];
    float* out = (float*)d_out;

    char* ws = (char*)d_ws;
    u16* xb    = (u16*)ws;  ws += (size_t)4096 * 1024 * 2;     // 8 MB
    u16* wqkvT = (u16*)ws;  ws += (size_t)3072 * 1024 * 2;     // 6 MB
    u16* woutT = (u16*)ws;  ws += (size_t)1024 * 1024 * 2;     // 2 MB
    u16* qb    = (u16*)ws;  ws += (size_t)64 * 1024 * 64 * 2;  // 8 MB
    u16* kb    = (u16*)ws;  ws += (size_t)64 * 1024 * 64 * 2;  // 8 MB
    u16* vtb   = (u16*)ws;  ws += (size_t)64 * 64 * 1024 * 2;  // 8 MB
    u16* attnb = (u16*)ws;  ws += (size_t)4 * 1024 * 1024 * 2; // 8 MB
    u8*  pq    = (u8*)ws;   ws += (size_t)64 * 1024 * 1024;    // 64 MB (fp8)

    kprep<<<3072, 256, 0, stream>>>(x, xb, Wqkv, wqkvT, Wout, woutT);
    kgemm_qkv<<<dim3(12, 16), 512, 0, stream>>>(xb, wqkvT, bqkv, qb, kb, vtb);
    kpq<<<1024, 256, 0, stream>>>(qb, pe, pq);
    kattn<<<512, 256, 0, stream>>>(qb, kb, vtb, pq, attnb);
    kgemm_out<<<dim3(8, 32), 256, 0, stream>>>(attnb, woutT, bout, out);
}

// Round 2
// 519.036 us; speedup vs baseline: 1.0168x; 1.0168x over previous
//
#include <hip/hip_runtime.h>
#include <cstdint>
#include <cstddef>

// ---------------------------------------------------------------------------
// MultiHeadAttention (linear attention + relative position bias, no softmax)
// B=4 S=1024 E=1024 H=16 D=64.  bf16 MFMA pipeline, fp8 Pq intermediate:
//   1. kprep     : x->bf16 ; W_qkv,W_out -> bf16 transposed  (merged)
//   2. kgemm_qkv : qkv = x@Wqkv + b ; scatter q/k (bh,s,d), v DIRECT as vt
//                  (m97 structure, 128^2 tile — the 256^2 8-phase attempt of
//                  r0 regressed: grid 192<256 CUs + 1 block/CU occupancy)
//   3. kpq       : Pq[bh][x][y] = sum_c pe[x,y,c]*q[bh,x,c] -> fp8, stored
//                  DIRECT from MFMA ACC fragments in permuted-y order
//   4. kattn     : O = ((QK^T + Pq)*scale) @ V ; Pq read as ONE uint4/lane.
//                  r1: double-buffered k/v tiles + counted vmcnt(6) gate +
//                  raw s_barrier (no per-iter vmcnt(0) drain) — 2-phase
//                  pipeline, stage of tile i+1 overlaps compute of tile i.
//   5. kgemm_out : out = attn@Wout + b (fp32)
// NOTE: ~380 us of dur_us is harness per-iteration overhead (1 GiB ws poison
// fill @ ~160 us + input restore); kernel-side total ~140 us vs ~95 us floor.
// ---------------------------------------------------------------------------

typedef unsigned short u16;
typedef unsigned char  u8;
typedef __bf16 bf16x8 __attribute__((ext_vector_type(8)));
typedef float  f32x4  __attribute__((ext_vector_type(4)));
typedef unsigned short u16x8 __attribute__((ext_vector_type(8)));

#define MFMA16(a, b, c) __builtin_amdgcn_mfma_f32_16x16x32_bf16((a), (b), (c), 0, 0, 0)

// async global->LDS, 16 B per lane; LDS dest = wave-uniform base + lane*16
#define GLOAD16(g, l)                                                        \
    __builtin_amdgcn_global_load_lds(                                        \
        (const __attribute__((address_space(1))) unsigned int*)(g),          \
        (__attribute__((address_space(3))) unsigned int*)(l), 16, 0, 0)

__device__ __forceinline__ u16 f2bf(float f) {
    __bf16 h = (__bf16)f;
    return __builtin_bit_cast(u16, h);
}
__device__ __forceinline__ u16x8 pack8(float4 a, float4 b) {
    u16x8 v;
    v[0] = f2bf(a.x); v[1] = f2bf(a.y); v[2] = f2bf(a.z); v[3] = f2bf(a.w);
    v[4] = f2bf(b.x); v[5] = f2bf(b.y); v[6] = f2bf(b.z); v[7] = f2bf(b.w);
    return v;
}

// raw barrier (NO implicit vmcnt(0) drain, unlike __syncthreads)
__device__ __forceinline__ void sbar() {
    asm volatile("" ::: "memory");
    __builtin_amdgcn_s_barrier();
    asm volatile("" ::: "memory");
}
template <int N> __device__ __forceinline__ void waitv() {
    asm volatile("s_waitcnt vmcnt(%0)" :: "n"(N) : "memory");
}

// --------------------------------------------------------------------------
// Merged prep: blocks [0,2048): x fp32->bf16 (8 elem/thread)
//              blocks [2048,2816): Wqkv (1024x3072) -> wqkvT (3072x1024) bf16
//              blocks [2816,3072): Wout (1024x1024) -> woutT bf16
// --------------------------------------------------------------------------
__device__ __forceinline__ void convT_tile(const float* __restrict__ in,
                                           u16* __restrict__ out, int R, int C,
                                           int bx, int by, float (*tile)[68]) {
    const int t  = threadIdx.x;
    const int r0 = by * 64, c0 = bx * 64;
    const int rr = t >> 4, c4 = t & 15;
    for (int p = 0; p < 4; ++p) {
        int r = rr + p * 16;
        float4 v = *(const float4*)&in[(size_t)(r0 + r) * C + c0 + c4 * 4];
        *(float4*)&tile[r][c4 * 4] = v;
    }
    __syncthreads();
    for (int p = 0; p < 4; ++p) {
        int n = rr + p * 16;
        ushort4 o;
        o.x = f2bf(tile[c4 * 4 + 0][n]);
        o.y = f2bf(tile[c4 * 4 + 1][n]);
        o.z = f2bf(tile[c4 * 4 + 2][n]);
        o.w = f2bf(tile[c4 * 4 + 3][n]);
        *(ushort4*)&out[(size_t)(c0 + n) * R + r0 + c4 * 4] = o;
    }
}

__global__ __launch_bounds__(256) void kprep(const float* __restrict__ x,
                                             u16* __restrict__ xb,
                                             const float* __restrict__ Wqkv,
                                             u16* __restrict__ wqkvT,
                                             const float* __restrict__ Wout,
                                             u16* __restrict__ woutT) {
    __shared__ float tile[64][68];
    const int bid = blockIdx.x;
    if (bid < 2048) {
        int i = (bid * 256 + threadIdx.x) * 8;
        float4 f0 = *(const float4*)&x[i];
        float4 f1 = *(const float4*)&x[i + 4];
        *(u16x8*)&xb[i] = pack8(f0, f1);
    } else if (bid < 2816) {
        int r = bid - 2048;                       // 48 x 16
        convT_tile(Wqkv, wqkvT, 1024, 3072, r % 48, r / 48, tile);
    } else {
        int r = bid - 2816;                       // 16 x 16
        convT_tile(Wout, woutT, 1024, 1024, r % 16, r / 16, tile);
    }
}

// --------------------------------------------------------------------------
// QKV GEMM (m97-style): C(4096x3072) = Xb(bf16) @ WT(3072x1024)^T + bias
// Epilogue: q,k -> (bh,s,d) scatter; v -> vt (bh,d,s) DIRECT (ushort4).
// grid (24,32), block 256
// --------------------------------------------------------------------------
__global__ __launch_bounds__(256, 2) void kgemm_qkv(const u16* __restrict__ A,
                                                    const u16* __restrict__ WT,
                                                    const float* __restrict__ bias,
                                                    u16* __restrict__ qb,
                                                    u16* __restrict__ kb,
                                                    u16* __restrict__ vtb) {
    __shared__ u16 a_s[128 * 64];
    __shared__ u16 b_s[128 * 64];
    const int t = threadIdx.x;
    const int m0 = blockIdx.y * 128, n0 = blockIdx.x * 128;
    const int lane = t & 63, w = t >> 6, lm = lane & 15, lq = lane >> 4;
    const int mb = (w >> 1) * 64, nb = (w & 1) * 64;
    const int sr = t >> 3, sc = (t & 7) * 8;

    f32x4 acc[4][4] = {};
    for (int k0 = 0; k0 < 1024; k0 += 64) {
        __syncthreads();
#pragma unroll
        for (int p = 0; p < 4; ++p) {
            GLOAD16(&A [(size_t)(m0 + p * 32 + sr) * 1024 + k0 + sc], &a_s[p * 2048 + t * 8]);
            GLOAD16(&WT[(size_t)(n0 + p * 32 + sr) * 1024 + k0 + sc], &b_s[p * 2048 + t * 8]);
        }
        __syncthreads();
#pragma unroll
        for (int ks = 0; ks < 2; ++ks) {
            bf16x8 af[4], bfr[4];
#pragma unroll
            for (int mt = 0; mt < 4; ++mt)
                af[mt] = *(const bf16x8*)&a_s[(mb + mt * 16 + lm) * 64 + ks * 32 + lq * 8];
#pragma unroll
            for (int nt = 0; nt < 4; ++nt)
                bfr[nt] = *(const bf16x8*)&b_s[(nb + nt * 16 + lm) * 64 + ks * 32 + lq * 8];
#pragma unroll
            for (int mt = 0; mt < 4; ++mt)
#pragma unroll
                for (int nt = 0; nt < 4; ++nt)
                    acc[mt][nt] = MFMA16(af[mt], bfr[nt], acc[mt][nt]);
        }
    }
    for (int nt = 0; nt < 4; ++nt) {
        int col = n0 + nb + nt * 16 + lm;
        float bv = bias[col];
        int which = col >> 10;
        int h = (col >> 6) & 15, d = col & 63;
        for (int mt = 0; mt < 4; ++mt) {
            int row0 = m0 + mb + mt * 16 + lq * 4;
            int b = row0 >> 10, s = row0 & 1023;
            if (which == 2) {                     // vt[bh][d][s] coalesced ushort4
                ushort4 o;
                o.x = f2bf(acc[mt][nt][0] + bv);
                o.y = f2bf(acc[mt][nt][1] + bv);
                o.z = f2bf(acc[mt][nt][2] + bv);
                o.w = f2bf(acc[mt][nt][3] + bv);
                *(ushort4*)&vtb[((size_t)(b * 16 + h) * 64 + d) * 1024 + s] = o;
            } else {
                u16* dst = (which == 0) ? qb : kb;
                for (int i = 0; i < 4; ++i)
                    dst[((size_t)((b * 16 + h) * 1024 + s + i)) * 64 + d] =
                        f2bf(acc[mt][nt][i] + bv);
            }
        }
    }
}

// --------------------------------------------------------------------------
// Pq[bh][x][y] = sum_c pe[x,y,c]*q[bh,x,c] -> fp8 e4m3 (scale in kattn)
// One block per x; pe streamed once device-wide; double-buffered pe_s,
// ONE barrier/iter; output stored DIRECT from ACC fragments:
//   byte offset within 64-y group = lq*16 + w*4 + i  (y = w*16 + lq*4 + i)
// grid 1024, block 256
// --------------------------------------------------------------------------
__global__ __launch_bounds__(256, 4) void kpq(const u16* __restrict__ qb,
                                              const float* __restrict__ pe,
                                              u8* __restrict__ Pq) {
    __shared__ u16 q_s[64 * 64];
    __shared__ u16 pe_s[2][64 * 80];
    const int x = blockIdx.x;
    const int t = threadIdx.x;
    const int lane = t & 63, w = t >> 6, lm = lane & 15, lq = lane >> 4;
#pragma unroll
    for (int p = 0; p < 2; ++p)
        GLOAD16(&qb[(size_t)((p * 32 + (t >> 3)) * 1024 + x) * 64 + (t & 7) * 8],
                &q_s[p * 2048 + t * 8]);
    const int yl = t >> 2, cq = (t & 3) * 16;
    const float* pex = pe + (size_t)x * 65536;
    float4 r0, r1, r2, r3;
    {
        const float* src = &pex[(size_t)yl * 64 + cq];
        r0 = *(const float4*)&src[0];  r1 = *(const float4*)&src[4];
        r2 = *(const float4*)&src[8];  r3 = *(const float4*)&src[12];
    }
    // per-lane fragment store base: bh = nt*16+lm, row x, group byte lq*16+w*4
    u8* pq_base = Pq + ((size_t)lm * 1024 + x) * 1024 + lq * 16 + w * 4;
    int cur = 0;
    for (int it = 0; it < 16; ++it) {
        *(u16x8*)&pe_s[cur][yl * 80 + cq]     = pack8(r0, r1);
        *(u16x8*)&pe_s[cur][yl * 80 + cq + 8] = pack8(r2, r3);
        __syncthreads();                        // pe_s[cur] ready (covers q_s on it=0)
        if (it < 15) {                          // prefetch next chunk
            const float* src = &pex[(size_t)((it + 1) * 64 + yl) * 64 + cq];
            r0 = *(const float4*)&src[0];  r1 = *(const float4*)&src[4];
            r2 = *(const float4*)&src[8];  r3 = *(const float4*)&src[12];
        }
        // D[y][bh]: wave w owns y-strip [16w, 16w+16)
        f32x4 acc[4] = {};
#pragma unroll
        for (int ks = 0; ks < 2; ++ks) {
            bf16x8 a = *(const bf16x8*)&pe_s[cur][(16 * w + lm) * 80 + ks * 32 + lq * 8];
#pragma unroll
            for (int nt = 0; nt < 4; ++nt) {
                bf16x8 b = *(const bf16x8*)&q_s[(nt * 16 + lm) * 64 + ks * 32 + lq * 8];
                acc[nt] = MFMA16(a, b, acc[nt]);
            }
        }
        // store fragments direct: lane holds bh=nt*16+lm, 4 consecutive y
#pragma unroll
        for (int nt = 0; nt < 4; ++nt) {
            unsigned int pw;
            pw = __builtin_amdgcn_cvt_pk_fp8_f32(acc[nt][0], acc[nt][1], 0u, false);
            pw = __builtin_amdgcn_cvt_pk_fp8_f32(acc[nt][2], acc[nt][3], pw, true);
            *(unsigned int*)&pq_base[(size_t)nt * 16 * 1024 * 1024 + it * 64] = pw;
        }
        cur ^= 1;
    }
}

// --------------------------------------------------------------------------
// Fused attention: O[x,d] = sum_y (q_x.k_y + Pq[x,y])*scale * v[y,d]
// bid = xt*64 + bh  ->  bid%8 = bh%8: all 8 x-tiles of a bh on one XCD.
// Pq: ONE uint4 per (nt,y0) per lane; component mt = y {y0+mt*16+lq*4..+3}.
// r1: k/v double-buffered (tile i in buf i&1); per iter:
//   sbar(A) [WAR: all waves done reading buf^1] -> stage tile i+1 -> pq4
//   -> vmcnt(6) [tile i resident; leaves stage(4)+pq4(2) in flight]
//   -> sbar(B) -> compute.  Last iter peeled with vmcnt(2).
// grid 512, block 256, LDS 68 KB -> 2 blocks/CU
// --------------------------------------------------------------------------
__global__ __launch_bounds__(256, 2) void kattn(const u16* __restrict__ qb,
                                                const u16* __restrict__ kb,
                                                const u16* __restrict__ vt,
                                                const u8* __restrict__ Pq,
                                                u16* __restrict__ attnb) {
    __shared__ u16 q_s[128 * 64];
    __shared__ u16 k_s[2][64 * 64];
    __shared__ u16 v_s[2][64 * 64];     // vt tile: rows d, cols y
    __shared__ u16 s_s[128 * 80];       // S tile (x rows, y cols), wave-private strips
    const int bid = blockIdx.x;
    const int bh = bid & 63, x0 = (bid >> 6) * 128;
    const int t = threadIdx.x;
    const int lane = t & 63, w = t >> 6, lm = lane & 15, lq = lane >> 4;
    const int sr = t >> 3, sc = (t & 7) * 8;

    // prologue: q (4 loads) + k/v tile 0 -> buf 0 (4 loads)
#pragma unroll
    for (int p = 0; p < 4; ++p)
        GLOAD16(&qb[(size_t)(bh * 1024 + x0 + p * 32 + sr) * 64 + sc],
                &q_s[p * 2048 + t * 8]);
#pragma unroll
    for (int p = 0; p < 2; ++p) {
        GLOAD16(&kb[(size_t)(bh * 1024 + p * 32 + sr) * 64 + sc],
                &k_s[0][p * 2048 + t * 8]);
        GLOAD16(&vt[(size_t)(bh * 64 + p * 32 + sr) * 1024 + sc],
                &v_s[0][p * 2048 + t * 8]);
    }

    const u8* PqRow = Pq + ((size_t)(bh * 1024) + x0 + 32 * w + lm) * 1024 + lq * 16;
    f32x4 oacc[2][4] = {};

#define ATTN_COMPUTE(CUR, Y0)                                                  \
    {                                                                          \
        /* S^T = K.Q^T : D[y][x]; wave w owns x-strip [32w, 32w+32) */         \
        f32x4 sacc[4][2] = {};                                                 \
        _Pragma("unroll")                                                      \
        for (int ks = 0; ks < 2; ++ks) {                                       \
            bf16x8 bq[2];                                                      \
            _Pragma("unroll")                                                  \
            for (int nt = 0; nt < 2; ++nt)                                     \
                bq[nt] = *(const bf16x8*)&q_s[(32 * w + nt * 16 + lm) * 64 + ks * 32 + lq * 8]; \
            _Pragma("unroll")                                                  \
            for (int mt = 0; mt < 4; ++mt) {                                   \
                bf16x8 ak = *(const bf16x8*)&k_s[CUR][(mt * 16 + lm) * 64 + ks * 32 + lq * 8]; \
                _Pragma("unroll")                                              \
                for (int nt = 0; nt < 2; ++nt)                                 \
                    sacc[mt][nt] = MFMA16(ak, bq[nt], sacc[mt][nt]);           \
            }                                                                  \
        }                                                                      \
        /* s = (qk + pq) * scale -> bf16 -> s_s (wave-private strip) */        \
        _Pragma("unroll")                                                      \
        for (int nt = 0; nt < 2; ++nt) {                                       \
            int xl = 32 * w + nt * 16 + lm;                                    \
            const unsigned int* pqc = (const unsigned int*)&pq4[nt];           \
            _Pragma("unroll")                                                  \
            for (int mt = 0; mt < 4; ++mt) {                                   \
                unsigned int pw = pqc[mt];                                     \
                ushort4 o;                                                     \
                o.x = f2bf((sacc[mt][nt][0] + __builtin_amdgcn_cvt_f32_fp8(pw, 0)) * 0.125f); \
                o.y = f2bf((sacc[mt][nt][1] + __builtin_amdgcn_cvt_f32_fp8(pw, 1)) * 0.125f); \
                o.z = f2bf((sacc[mt][nt][2] + __builtin_amdgcn_cvt_f32_fp8(pw, 2)) * 0.125f); \
                o.w = f2bf((sacc[mt][nt][3] + __builtin_amdgcn_cvt_f32_fp8(pw, 3)) * 0.125f); \
                *(ushort4*)&s_s[xl * 80 + mt * 16 + lq * 4] = o;               \
            }                                                                  \
        }                                                                      \
        /* O += S.V  (A = s_s own strip, B = v_s) */                           \
        _Pragma("unroll")                                                      \
        for (int ks = 0; ks < 2; ++ks) {                                       \
            bf16x8 as[2];                                                      \
            _Pragma("unroll")                                                  \
            for (int mt = 0; mt < 2; ++mt)                                     \
                as[mt] = *(const bf16x8*)&s_s[(32 * w + mt * 16 + lm) * 80 + ks * 32 + lq * 8]; \
            _Pragma("unroll")                                                  \
            for (int nt = 0; nt < 4; ++nt) {                                   \
                bf16x8 bv = *(const bf16x8*)&v_s[CUR][(nt * 16 + lm) * 64 + ks * 32 + lq * 8]; \
                _Pragma("unroll")                                              \
                for (int mt = 0; mt < 2; ++mt)                                 \
                    oacc[mt][nt] = MFMA16(as[mt], bv, oacc[mt][nt]);           \
            }                                                                  \
        }                                                                      \
    }

    int cur = 0;
#pragma unroll 1
    for (int it = 0; it < 15; ++it) {
        const int y0 = it * 64;
        sbar();                                // (A) buf[cur^1] reads done
        // stage tile it+1 into buf[cur^1]
#pragma unroll
        for (int p = 0; p < 2; ++p) {
            GLOAD16(&kb[(size_t)(bh * 1024 + y0 + 64 + p * 32 + sr) * 64 + sc],
                    &k_s[cur ^ 1][p * 2048 + t * 8]);
            GLOAD16(&vt[(size_t)(bh * 64 + p * 32 + sr) * 1024 + y0 + 64 + sc],
                    &v_s[cur ^ 1][p * 2048 + t * 8]);
        }
        uint4 pq4[2];
#pragma unroll
        for (int nt = 0; nt < 2; ++nt)
            pq4[nt] = *(const uint4*)&PqRow[(size_t)(nt * 16) * 1024 + y0];
        waitv<6>();                            // tile it resident (own wave)
        sbar();                                // (B) tile it resident (all waves)
        ATTN_COMPUTE(cur, y0)
        cur ^= 1;
    }
    {                                          // peeled last iter (it=15)
        uint4 pq4[2];
#pragma unroll
        for (int nt = 0; nt < 2; ++nt)
            pq4[nt] = *(const uint4*)&PqRow[(size_t)(nt * 16) * 1024 + 960];
        waitv<2>();                            // tile 15 resident (pq4 in flight)
        sbar();
        ATTN_COMPUTE(cur, 960)
    }
#undef ATTN_COMPUTE

    // write attn (B, S, E=h*64+d) bf16
    const int b = bh >> 4, h = bh & 15;
    for (int mt = 0; mt < 2; ++mt) {
        for (int nt = 0; nt < 4; ++nt) {
            int d = nt * 16 + lm;
            for (int i = 0; i < 4; ++i) {
                int s = x0 + 32 * w + mt * 16 + lq * 4 + i;
                attnb[((size_t)(b * 1024 + s)) * 1024 + h * 64 + d] = f2bf(oacc[mt][nt][i]);
            }
        }
    }
}

// --------------------------------------------------------------------------
// Out projection (m97-style): out(4096x1024 fp32) = attn(bf16)@WoutT^T + b
// grid (8,32), block 256
// --------------------------------------------------------------------------
__global__ __launch_bounds__(256, 2) void kgemm_out(const u16* __restrict__ A,
                                                    const u16* __restrict__ WT,
                                                    const float* __restrict__ bias,
                                                    float* __restrict__ out) {
    __shared__ u16 a_s[128 * 64];
    __shared__ u16 b_s[128 * 64];
    const int t = threadIdx.x;
    const int m0 = blockIdx.y * 128, n0 = blockIdx.x * 128;
    const int lane = t & 63, w = t >> 6, lm = lane & 15, lq = lane >> 4;
    const int mb = (w >> 1) * 64, nb = (w & 1) * 64;
    const int sr = t >> 3, sc = (t & 7) * 8;

    f32x4 acc[4][4] = {};
    for (int k0 = 0; k0 < 1024; k0 += 64) {
        __syncthreads();
#pragma unroll
        for (int p = 0; p < 4; ++p) {
            GLOAD16(&A [(size_t)(m0 + p * 32 + sr) * 1024 + k0 + sc], &a_s[p * 2048 + t * 8]);
            GLOAD16(&WT[(size_t)(n0 + p * 32 + sr) * 1024 + k0 + sc], &b_s[p * 2048 + t * 8]);
        }
        __syncthreads();
#pragma unroll
        for (int ks = 0; ks < 2; ++ks) {
            bf16x8 af[4], bfr[4];
#pragma unroll
            for (int mt = 0; mt < 4; ++mt)
                af[mt] = *(const bf16x8*)&a_s[(mb + mt * 16 + lm) * 64 + ks * 32 + lq * 8];
#pragma unroll
            for (int nt = 0; nt < 4; ++nt)
                bfr[nt] = *(const bf16x8*)&b_s[(nb + nt * 16 + lm) * 64 + ks * 32 + lq * 8];
#pragma unroll
            for (int mt = 0; mt < 4; ++mt)
#pragma unroll
                for (int nt = 0; nt < 4; ++nt)
                    acc[mt][nt] = MFMA16(af[mt], bfr[nt], acc[mt][nt]);
        }
    }
    for (int nt = 0; nt < 4; ++nt) {
        int col = n0 + nb + nt * 16 + lm;
        float bv = bias[col];
        for (int mt = 0; mt < 4; ++mt) {
            for (int i = 0; i < 4; ++i) {
                int row = m0 + mb + mt * 16 + lq * 4 + i;
                out[(size_t)row * 1024 + col] = acc[mt][nt][i] + bv;
            }
        }
    }
}

// --------------------------------------------------------------------------
extern "C" void kernel_launch(void* const* d_in, const int* in_sizes, int n_in,
                              void* d_out, int out_size, void* d_ws, size_t ws_size,
                              hipStream_t stream) {
    (void)in_sizes; (void)n_in; (void)out_size; (void)ws_size;
    const float* x    = (const float*)d_in[0];
    const float* Wqkv = (const float*)d_in[1];
    const float* bqkv = (const float*)d_in[2];
    const float* pe   = (const float*)d_in[3];
    const float* Wout = (const float*)d_in[4];
    const float* bout = (const float*)d_in[5];
    float* out = (float*)d_out;

    char* ws = (char*)d_ws;
    u16* xb    = (u16*)ws;  ws += (size_t)4096 * 1024 * 2;     // 8 MB
    u16* wqkvT = (u16*)ws;  ws += (size_t)3072 * 1024 * 2;     // 6 MB
    u16* woutT = (u16*)ws;  ws += (size_t)1024 * 1024 * 2;     // 2 MB
    u16* qb    = (u16*)ws;  ws += (size_t)64 * 1024 * 64 * 2;  // 8 MB
    u16* kb    = (u16*)ws;  ws += (size_t)64 * 1024 * 64 * 2;  // 8 MB
    u16* vtb   = (u16*)ws;  ws += (size_t)64 * 64 * 1024 * 2;  // 8 MB
    u16* attnb = (u16*)ws;  ws += (size_t)4 * 1024 * 1024 * 2; // 8 MB
    u8*  pq    = (u8*)ws;   ws += (size_t)64 * 1024 * 1024;    // 64 MB (fp8)

    kprep<<<3072, 256, 0, stream>>>(x, xb, Wqkv, wqkvT, Wout, woutT);
    kgemm_qkv<<<dim3(24, 32), 256, 0, stream>>>(xb, wqkvT, bqkv, qb, kb, vtb);
    kpq<<<1024, 256, 0, stream>>>(qb, pe, pq);
    kattn<<<512, 256, 0, stream>>>(qb, kb, vtb, pq, attnb);
    kgemm_out<<<dim3(8, 32), 256, 0, stream>>>(attnb, woutT, bout, out);
}